// Round 3
// baseline (29.045 us; speedup 1.0000x reference)
//
#include <hip/hip_runtime.h>

// out[i] = MLP(emb_user[uid[i]]) + MLP(emb_movie[mid[i]])
// bf16 MFMA 16x16x32, fp32 acc.  Two kernels:
//   prep_w2: convert W2 [256][128] f32 -> 64 bf16 A-fragments in d_ws.
//   main:    W1 frags in LDS (32KB), W2 frags streamed from global (L2/L1-
//            resident, coalesced base+lane*16), h1 double-buffered in LDS
//            (per-wave, 2x4KB) with software pipelining: produce chunk hq+1
//            between the write and the read of chunk hq.
// 256-thr blocks (4 waves, 32 samples/wave) -> 512 blocks, LDS 64KB ->
// 2 blocks/CU so gather/stage of one block hides under MFMA of the other.

typedef __attribute__((ext_vector_type(8))) short bf16x8;
typedef __attribute__((ext_vector_type(4))) float f32x4;

__device__ __forceinline__ unsigned int bfr(float f) {   // RNE bf16, low 16
  unsigned int u = __builtin_bit_cast(unsigned int, f);
  return (u + 0x7fffu + ((u >> 16) & 1u)) >> 16;
}
__device__ __forceinline__ unsigned int bfrh(float f) {  // RNE bf16, high 16
  unsigned int u = __builtin_bit_cast(unsigned int, f);
  return (u + 0x7fffu + ((u >> 16) & 1u)) & 0xffff0000u;
}
__device__ __forceinline__ unsigned int pk2(float lo, float hi) {
  return bfr(lo) | bfrh(hi);
}

// ---- prep: W2 -> bf16 A-frag order in d_ws ----
// frag fi = nt2*8+hq; lane l=g*16+mm holds W2[k=32hq+8g+j][16nt2+mm], j=0..7.
__global__ __launch_bounds__(256) void prep_w2(const float* __restrict__ W2,
                                               unsigned short* __restrict__ w2g) {
  const int t = blockIdx.x * 256 + threadIdx.x;  // 0..4095
  const int fi = t >> 6, l = t & 63;
  const int g = l >> 4, mm = l & 15;
  const int nt2 = fi >> 3, hq = fi & 7;
  const float* src = W2 + (hq * 32 + 8 * g) * 128 + nt2 * 16 + mm;
  uint4 o;
  o.x = pk2(src[0 * 128], src[1 * 128]);
  o.y = pk2(src[2 * 128], src[3 * 128]);
  o.z = pk2(src[4 * 128], src[5 * 128]);
  o.w = pk2(src[6 * 128], src[7 * 128]);
  *(uint4*)&w2g[fi * 512 + l * 8] = o;
}

__global__ __launch_bounds__(256, 2) void movielens_mlp(
    const int* __restrict__ uids, const int* __restrict__ mids,
    const float* __restrict__ EU, const float* __restrict__ EM,
    const float* __restrict__ W1, const float* __restrict__ B1,
    const unsigned short* __restrict__ w2g, const float* __restrict__ B2,
    const float* __restrict__ W3, const float* __restrict__ B3,
    float* __restrict__ out) {
  __shared__ __align__(16) unsigned short w1f[16 * 2 * 512];    // 32 KB
  __shared__ __align__(16) unsigned short h1f[4 * 2 * 4 * 512]; // 32 KB

  const int tid = threadIdx.x;
  const int lane = tid & 63, wv = tid >> 6;
  const int m = lane & 15, g = lane >> 4;

  const int sbase = blockIdx.x * 128 + wv * 32;
  const int su = sbase + m, sv = su + 16;

  // ---- issue embedding gathers first (longest latency chain) ----
  const float* rp[4];
  rp[0] = EU + (size_t)uids[su] * 64;
  rp[1] = EU + (size_t)uids[sv] * 64;
  rp[2] = EM + (size_t)mids[su] * 64;
  rp[3] = EM + (size_t)mids[sv] * 64;
  float4 xr[4][2][2];
#pragma unroll
  for (int mt = 0; mt < 4; ++mt)
#pragma unroll
    for (int kt = 0; kt < 2; ++kt) {
      xr[mt][kt][0] = *(const float4*)(rp[mt] + kt * 32 + 8 * g);
      xr[mt][kt][1] = *(const float4*)(rp[mt] + kt * 32 + 8 * g + 4);
    }

  // ---- stage W1 into fragment order (overlaps with gather flight) ----
  {
    const int u = tid & 63;
#pragma unroll
    for (int pass = 0; pass < 4; ++pass) {
      const int qd = (tid >> 6) + 4 * pass;  // k-quad 0..15
      const float* src = W1 + (qd * 4) * 256 + 4 * u;
      const float4 r0 = *(const float4*)(src);
      const float4 r1 = *(const float4*)(src + 256);
      const float4 r2 = *(const float4*)(src + 512);
      const float4 r3 = *(const float4*)(src + 768);
      const float c0[4] = {r0.x, r0.y, r0.z, r0.w};
      const float c1[4] = {r1.x, r1.y, r1.z, r1.w};
      const float c2[4] = {r2.x, r2.y, r2.z, r2.w};
      const float c3[4] = {r3.x, r3.y, r3.z, r3.w};
      const int kt = qd >> 3, gg = (qd >> 1) & 3, bo = (qd & 1) * 4;
#pragma unroll
      for (int p = 0; p < 4; ++p) {
        const int n = 4 * u + p, nt = n >> 4, mm = n & 15;
        uint2 pk;
        pk.x = pk2(c0[p], c1[p]);
        pk.y = pk2(c2[p], c3[p]);
        *(uint2*)&w1f[(nt * 2 + kt) * 512 + (gg * 16 + mm) * 8 + bo] = pk;
      }
    }
  }

  // ---- convert gathers to B-frags ----
  bf16x8 xf[4][2];
#pragma unroll
  for (int mt = 0; mt < 4; ++mt)
#pragma unroll
    for (int kt = 0; kt < 2; ++kt) {
      const float4 a = xr[mt][kt][0], b = xr[mt][kt][1];
      uint4 t;
      t.x = pk2(a.x, a.y);
      t.y = pk2(a.z, a.w);
      t.z = pk2(b.x, b.y);
      t.w = pk2(b.z, b.w);
      xf[mt][kt] = __builtin_bit_cast(bf16x8, t);
    }
  __syncthreads();

  unsigned short* __restrict__ h1 = &h1f[wv * 4096];  // 2 bufs x 4 frags

  // layer-1 producer for chunk hq into buf
  auto produce = [&](int hq, unsigned short* buf) {
#pragma unroll
    for (int ntloc = 0; ntloc < 2; ++ntloc) {
      const int fb = (hq * 4 + ntloc * 2) * 512;
      const bf16x8 wa0 = *(const bf16x8*)&w1f[fb + lane * 8];
      const bf16x8 wa1 = *(const bf16x8*)&w1f[fb + 512 + lane * 8];
      const float4 b1v = *(const float4*)(B1 + hq * 32 + ntloc * 16 + 4 * g);
      const int wo = ((2 * ntloc + (g >> 1)) * 16 + m) * 8 + (g & 1) * 4;
#pragma unroll
      for (int mt = 0; mt < 4; ++mt) {
        f32x4 acc;
        acc[0] = b1v.x; acc[1] = b1v.y; acc[2] = b1v.z; acc[3] = b1v.w;
        acc = __builtin_amdgcn_mfma_f32_16x16x32_bf16(wa0, xf[mt][0], acc, 0, 0, 0);
        acc = __builtin_amdgcn_mfma_f32_16x16x32_bf16(wa1, xf[mt][1], acc, 0, 0, 0);
        uint2 pk;
        pk.x = pk2(fmaxf(acc[0], 0.f), fmaxf(acc[1], 0.f));
        pk.y = pk2(fmaxf(acc[2], 0.f), fmaxf(acc[3], 0.f));
        *(uint2*)&buf[mt * 512 + wo] = pk;
      }
    }
  };

  // layer-2 accumulators, bias-initialized
  f32x4 acc2[4][8];
#pragma unroll
  for (int nt2 = 0; nt2 < 8; ++nt2) {
    const float4 bv = *(const float4*)(B2 + nt2 * 16 + 4 * g);
#pragma unroll
    for (int mt = 0; mt < 4; ++mt) {
      acc2[mt][nt2][0] = bv.x; acc2[mt][nt2][1] = bv.y;
      acc2[mt][nt2][2] = bv.z; acc2[mt][nt2][3] = bv.w;
    }
  }

  produce(0, h1);  // prologue into buf 0

#pragma unroll 2
  for (int hq = 0; hq < 8; ++hq) {
    // issue W2 frag loads for this chunk (latency covered by produce below)
    bf16x8 w2v[8];
#pragma unroll
    for (int nt2 = 0; nt2 < 8; ++nt2)
      w2v[nt2] = *(const bf16x8*)&w2g[(nt2 * 8 + hq) * 512 + lane * 8];
    // produce next chunk between the write and the read of current chunk
    if (hq < 7) produce(hq + 1, h1 + ((hq + 1) & 1) * 2048);
    unsigned short* cbuf = h1 + (hq & 1) * 2048;
    bf16x8 hf[4];
#pragma unroll
    for (int mt = 0; mt < 4; ++mt)
      hf[mt] = *(const bf16x8*)&cbuf[mt * 512 + lane * 8];
#pragma unroll
    for (int nt2 = 0; nt2 < 8; ++nt2)
#pragma unroll
      for (int mt = 0; mt < 4; ++mt)
        acc2[mt][nt2] = __builtin_amdgcn_mfma_f32_16x16x32_bf16(
            w2v[nt2], hf[mt], acc2[mt][nt2], 0, 0, 0);
  }

  // ---- layer 3: relu(h2) . W3, reduce over g-groups ----
  const float b3v = B3[0];
  float part[4] = {0.f, 0.f, 0.f, 0.f};
#pragma unroll
  for (int nt2 = 0; nt2 < 8; ++nt2) {
    const float4 w3v = *(const float4*)(W3 + nt2 * 16 + 4 * g);
#pragma unroll
    for (int mt = 0; mt < 4; ++mt) {
      const f32x4 c = acc2[mt][nt2];
      part[mt] += fmaxf(c[0], 0.f) * w3v.x + fmaxf(c[1], 0.f) * w3v.y +
                  fmaxf(c[2], 0.f) * w3v.z + fmaxf(c[3], 0.f) * w3v.w;
    }
  }
#pragma unroll
  for (int mt = 0; mt < 4; ++mt) {
    part[mt] += __shfl_xor(part[mt], 16, 64);
    part[mt] += __shfl_xor(part[mt], 32, 64);
  }
  if (lane < 16) {
    out[sbase + lane] = part[0] + part[2] + 2.f * b3v;
  } else if (lane < 32) {
    out[sbase + lane] = part[1] + part[3] + 2.f * b3v;
  }
}

extern "C" void kernel_launch(void* const* d_in, const int* in_sizes, int n_in,
                              void* d_out, int out_size, void* d_ws, size_t ws_size,
                              hipStream_t stream) {
  const int* uids = (const int*)d_in[0];
  const int* mids = (const int*)d_in[1];
  const float* EU = (const float*)d_in[2];
  const float* EM = (const float*)d_in[3];
  const float* W1 = (const float*)d_in[4];
  const float* B1 = (const float*)d_in[5];
  const float* W2 = (const float*)d_in[6];
  const float* B2 = (const float*)d_in[7];
  const float* W3 = (const float*)d_in[8];
  const float* B3 = (const float*)d_in[9];
  float* out = (float*)d_out;
  unsigned short* w2g = (unsigned short*)d_ws;  // 64 KB of frag-ordered bf16

  hipLaunchKernelGGL(prep_w2, dim3(16), dim3(256), 0, stream, W2, w2g);

  const int B = in_sizes[0];  // 65536
  const int nblk = B / 128;   // 512 blocks, 128 samples each
  hipLaunchKernelGGL(movielens_mlp, dim3(nblk), dim3(256), 0, stream,
                     uids, mids, EU, EM, W1, B1, w2g, B2, W3, B3, out);
}

// Round 4
// 22.248 us; speedup vs baseline: 1.3055x; 1.3055x over previous
//
#include <hip/hip_runtime.h>

// out[i] = MLP(emb_user[uid[i]]) + MLP(emb_movie[mid[i]])
// bf16 MFMA 16x16x32, fp32 acc, single kernel.
//
// Key idea: sigma-permuted W1 makes the layer1->layer2 handoff REGISTER-ONLY.
// Layer1 computes h^T = W1'^T x^T. Producer lane (g,m), tile nt, reg r holds
// D position p=16nt+4g+r. Storing W1' so position p carries logical channel
// c = 8g+4nt+r means each lane's 8 accumulators are exactly the 8 channels
// {8g..8g+7} its own layer-2 B-fragment needs: pack pairwise with
// v_cvt_pk_bf16_f32 and feed MFMA directly. No h1 LDS buffer, no shuffles.
// W2 needs no permutation (channel c sits at hardware k=c).
//
// LDS: w1f 32KB (sigma-permuted A-frags) + w2f 64KB (A-frags) = 96KB.
// 512 thr = 8 waves; wave owns 32 samples as 4 m-tiles (2 user + 2 movie).
// Grid 256 = 1 block/CU, 2 waves/SIMD. One barrier total (after staging).
// Gathers issued first; staging overlaps their HBM flight (caches are
// flushed between replays by the harness's 1GB fills).

typedef __attribute__((ext_vector_type(8))) short bf16x8;
typedef __attribute__((ext_vector_type(4))) float f32x4;

__device__ __forceinline__ unsigned int cvt_pk(float lo, float hi) {
  unsigned int r;
  asm("v_cvt_pk_bf16_f32 %0, %1, %2" : "=v"(r) : "v"(lo), "v"(hi));
  return r;  // bf16(lo) in [15:0], bf16(hi) in [31:16], RNE
}

__global__ __launch_bounds__(512, 2) void movielens_mlp(
    const int* __restrict__ uids, const int* __restrict__ mids,
    const float* __restrict__ EU, const float* __restrict__ EM,
    const float* __restrict__ W1, const float* __restrict__ B1,
    const float* __restrict__ W2, const float* __restrict__ B2,
    const float* __restrict__ W3, const float* __restrict__ B3,
    float* __restrict__ out) {
  __shared__ __align__(16) unsigned short w1f[16 * 2 * 512];  // 32 KB
  __shared__ __align__(16) unsigned short w2f[8 * 8 * 512];   // 64 KB

  const int tid = threadIdx.x;
  const int lane = tid & 63, wv = tid >> 6;
  const int m = lane & 15, g = lane >> 4;

  const int sbase = blockIdx.x * 256 + wv * 32;
  const int su = sbase + m, sv = su + 16;

  // ---- issue embedding gathers first (longest latency: HBM, cold) ----
  const float* rp[4];
  rp[0] = EU + (size_t)uids[su] * 64;
  rp[1] = EU + (size_t)uids[sv] * 64;
  rp[2] = EM + (size_t)mids[su] * 64;
  rp[3] = EM + (size_t)mids[sv] * 64;
  float4 xr[4][2][2];
#pragma unroll
  for (int mt = 0; mt < 4; ++mt)
#pragma unroll
    for (int kt = 0; kt < 2; ++kt) {
      xr[mt][kt][0] = *(const float4*)(rp[mt] + kt * 32 + 8 * g);
      xr[mt][kt][1] = *(const float4*)(rp[mt] + kt * 32 + 8 * g + 4);
    }

  // ---- stage W1 into sigma-permuted A-frag order (overlaps gather) ----
  {
    const int u = tid & 63;
#pragma unroll
    for (int pass = 0; pass < 2; ++pass) {
      const int qd = (tid >> 6) + 8 * pass;  // k-quad 0..15
      const float* src = W1 + (qd * 4) * 256 + 4 * u;
      const float4 r0 = *(const float4*)(src);
      const float4 r1 = *(const float4*)(src + 256);
      const float4 r2 = *(const float4*)(src + 512);
      const float4 r3 = *(const float4*)(src + 768);
      const float c0[4] = {r0.x, r0.y, r0.z, r0.w};
      const float c1[4] = {r1.x, r1.y, r1.z, r1.w};
      const float c2[4] = {r2.x, r2.y, r2.z, r2.w};
      const float c3[4] = {r3.x, r3.y, r3.z, r3.w};
      const int kt = qd >> 3, gg = (qd >> 1) & 3, bo = (qd & 1) * 4;
#pragma unroll
      for (int p = 0; p < 4; ++p) {
        const int n = 4 * u + p;          // logical channel c
        const int hq = n >> 5, cl = n & 31;
        // invert sigma: channel cl=8gp+4nt+r -> A-row mm=4gp+r, tile nt
        const int nt = (cl >> 2) & 1, mm = 4 * (cl >> 3) + (cl & 3);
        const int fi = hq * 4 + nt * 2 + kt;
        uint2 pk;
        pk.x = cvt_pk(c0[p], c1[p]);
        pk.y = cvt_pk(c2[p], c3[p]);
        *(uint2*)&w1f[fi * 512 + (gg * 16 + mm) * 8 + bo] = pk;
      }
    }
    // ---- stage W2 into (unpermuted) A-frag order ----
    const int u2 = tid & 31;
#pragma unroll
    for (int pass = 0; pass < 4; ++pass) {
      const int qd = (tid >> 5) + 16 * pass;  // k-quad 0..63
      const float* src = W2 + (qd * 4) * 128 + 4 * u2;
      const float4 r0 = *(const float4*)(src);
      const float4 r1 = *(const float4*)(src + 128);
      const float4 r2 = *(const float4*)(src + 256);
      const float4 r3 = *(const float4*)(src + 384);
      const float c0[4] = {r0.x, r0.y, r0.z, r0.w};
      const float c1[4] = {r1.x, r1.y, r1.z, r1.w};
      const float c2[4] = {r2.x, r2.y, r2.z, r2.w};
      const float c3[4] = {r3.x, r3.y, r3.z, r3.w};
      const int hq2 = qd >> 3, gg = (qd >> 1) & 3, bo = (qd & 1) * 4;
#pragma unroll
      for (int p = 0; p < 4; ++p) {
        const int n = 4 * u2 + p, nt2 = n >> 4, mm = n & 15;
        uint2 pk;
        pk.x = cvt_pk(c0[p], c1[p]);
        pk.y = cvt_pk(c2[p], c3[p]);
        *(uint2*)&w2f[(nt2 * 8 + hq2) * 512 + (gg * 16 + mm) * 8 + bo] = pk;
      }
    }
  }

  // ---- convert gathers to layer-1 B-frags ----
  bf16x8 xf[4][2];
#pragma unroll
  for (int mt = 0; mt < 4; ++mt)
#pragma unroll
    for (int kt = 0; kt < 2; ++kt) {
      const float4 a = xr[mt][kt][0], b = xr[mt][kt][1];
      uint4 t;
      t.x = cvt_pk(a.x, a.y);
      t.y = cvt_pk(a.z, a.w);
      t.z = cvt_pk(b.x, b.y);
      t.w = cvt_pk(b.z, b.w);
      xf[mt][kt] = __builtin_bit_cast(bf16x8, t);
    }
  __syncthreads();

  // ---- layer-2 accumulators, bias-initialized ----
  f32x4 acc2[4][8];
#pragma unroll
  for (int nt2 = 0; nt2 < 8; ++nt2) {
    const float4 bv = *(const float4*)(B2 + nt2 * 16 + 4 * g);
#pragma unroll
    for (int mt = 0; mt < 4; ++mt) {
      acc2[mt][nt2][0] = bv.x; acc2[mt][nt2][1] = bv.y;
      acc2[mt][nt2][2] = bv.z; acc2[mt][nt2][3] = bv.w;
    }
  }

  // ---- main loop: 8 chunks of 32 layer-1 channels, all in registers ----
#pragma unroll 2
  for (int hq = 0; hq < 8; ++hq) {
    uint4 hw[4];  // per m-tile: packed bf16x8 B-frag of h1 channels
#pragma unroll
    for (int nt = 0; nt < 2; ++nt) {
      const int fb = (hq * 4 + nt * 2) * 512;
      const bf16x8 wa0 = *(const bf16x8*)&w1f[fb + lane * 8];
      const bf16x8 wa1 = *(const bf16x8*)&w1f[fb + 512 + lane * 8];
      // sigma-permuted bias: reg r of (nt,g) is channel 32hq+8g+4nt+r
      const float4 b1v = *(const float4*)(B1 + hq * 32 + 8 * g + 4 * nt);
#pragma unroll
      for (int mt = 0; mt < 4; ++mt) {
        f32x4 acc;
        acc[0] = b1v.x; acc[1] = b1v.y; acc[2] = b1v.z; acc[3] = b1v.w;
        acc = __builtin_amdgcn_mfma_f32_16x16x32_bf16(wa0, xf[mt][0], acc, 0, 0, 0);
        acc = __builtin_amdgcn_mfma_f32_16x16x32_bf16(wa1, xf[mt][1], acc, 0, 0, 0);
        const unsigned int wlo = cvt_pk(fmaxf(acc[0], 0.f), fmaxf(acc[1], 0.f));
        const unsigned int whi = cvt_pk(fmaxf(acc[2], 0.f), fmaxf(acc[3], 0.f));
        if (nt == 0) { hw[mt].x = wlo; hw[mt].y = whi; }
        else         { hw[mt].z = wlo; hw[mt].w = whi; }
      }
    }
#pragma unroll
    for (int nt2 = 0; nt2 < 8; ++nt2) {
      const bf16x8 w2v = *(const bf16x8*)&w2f[(nt2 * 8 + hq) * 512 + lane * 8];
#pragma unroll
      for (int mt = 0; mt < 4; ++mt)
        acc2[mt][nt2] = __builtin_amdgcn_mfma_f32_16x16x32_bf16(
            w2v, __builtin_bit_cast(bf16x8, hw[mt]), acc2[mt][nt2], 0, 0, 0);
    }
  }

  // ---- layer 3: relu(h2) . W3, reduce across g-groups ----
  const float b3v = B3[0];
  float part[4] = {0.f, 0.f, 0.f, 0.f};
#pragma unroll
  for (int nt2 = 0; nt2 < 8; ++nt2) {
    const float4 w3v = *(const float4*)(W3 + nt2 * 16 + 4 * g);
#pragma unroll
    for (int mt = 0; mt < 4; ++mt) {
      const f32x4 c = acc2[mt][nt2];
      part[mt] += fmaxf(c[0], 0.f) * w3v.x + fmaxf(c[1], 0.f) * w3v.y +
                  fmaxf(c[2], 0.f) * w3v.z + fmaxf(c[3], 0.f) * w3v.w;
    }
  }
#pragma unroll
  for (int mt = 0; mt < 4; ++mt) {
    part[mt] += __shfl_xor(part[mt], 16, 64);
    part[mt] += __shfl_xor(part[mt], 32, 64);
  }
  if (lane < 16) {
    out[sbase + lane] = part[0] + part[2] + 2.f * b3v;
  } else if (lane < 32) {
    out[sbase + lane] = part[1] + part[3] + 2.f * b3v;
  }
}

extern "C" void kernel_launch(void* const* d_in, const int* in_sizes, int n_in,
                              void* d_out, int out_size, void* d_ws, size_t ws_size,
                              hipStream_t stream) {
  const int* uids = (const int*)d_in[0];
  const int* mids = (const int*)d_in[1];
  const float* EU = (const float*)d_in[2];
  const float* EM = (const float*)d_in[3];
  const float* W1 = (const float*)d_in[4];
  const float* B1 = (const float*)d_in[5];
  const float* W2 = (const float*)d_in[6];
  const float* B2 = (const float*)d_in[7];
  const float* W3 = (const float*)d_in[8];
  const float* B3 = (const float*)d_in[9];
  float* out = (float*)d_out;

  const int B = in_sizes[0];  // 65536
  const int nblk = B / 256;   // 256 blocks x 256 samples
  hipLaunchKernelGGL(movielens_mlp, dim3(nblk), dim3(512), 0, stream,
                     uids, mids, EU, EM, W1, B1, W2, B2, W3, B3, out);
}